// Round 1
// baseline (60.984 us; speedup 1.0000x reference)
//
#include <hip/hip_runtime.h>

// Problem: x [B=64, C=512, H=28, W=28] fp32.
// Forward math reduces to: out = relu(x - mean_over_C(x)) per (b,h,w).
// (top_k mask and stop_gradient only affect the backward pass.)

#define B_DIM 64
#define C_DIM 512
#define HW_DIM 784          // 28*28
#define HW4 196             // HW_DIM / 4 (float4 groups; 784 % 4 == 0)
#define TX 16               // float4-groups per block -> 64 positions/block
#define TY 16               // channel slices; each thread owns C_DIM/TY = 32 channels
#define CPT (C_DIM / TY)    // 32

__global__ __launch_bounds__(256) void kwinners_fwd(const float* __restrict__ x,
                                                    float* __restrict__ out) {
    __shared__ float4 red[TY * TX];   // 4 KB

    const int tid = threadIdx.x;
    const int tx  = tid & (TX - 1);
    const int ty  = tid >> 4;

    const int g   = blockIdx.x * TX + tx;   // global float4-group index, < B*HW4
    const int b   = g / HW4;
    const int hw4 = g - b * HW4;

    const float4* __restrict__ xb =
        reinterpret_cast<const float4*>(x) + (size_t)b * C_DIM * HW4;
    float4* __restrict__ ob =
        reinterpret_cast<float4*>(out) + (size_t)b * C_DIM * HW4;

    // ---- pass 1: partial channel sums for 4 positions ----
    const int c0 = ty * CPT;
    float4 s = make_float4(0.f, 0.f, 0.f, 0.f);
    #pragma unroll 8
    for (int cc = 0; cc < CPT; ++cc) {
        float4 v = xb[(size_t)(c0 + cc) * HW4 + hw4];
        s.x += v.x; s.y += v.y; s.z += v.z; s.w += v.w;
    }
    red[tid] = s;
    __syncthreads();

    // ---- LDS tree reduce across the TY channel slices ----
    #pragma unroll
    for (int step = TY / 2; step > 0; step >>= 1) {
        if (ty < step) {
            float4 a  = red[tid];
            float4 bb = red[(ty + step) * TX + tx];
            a.x += bb.x; a.y += bb.y; a.z += bb.z; a.w += bb.w;
            red[tid] = a;
        }
        __syncthreads();
    }

    float4 m = red[tx];               // row ty==0 holds totals; LDS broadcast
    const float inv = 1.0f / (float)C_DIM;
    m.x *= inv; m.y *= inv; m.z *= inv; m.w *= inv;

    // ---- pass 2: out = relu(x - mean); re-read hits L2/LLC ----
    #pragma unroll 8
    for (int cc = 0; cc < CPT; ++cc) {
        const size_t idx = (size_t)(c0 + cc) * HW4 + hw4;
        float4 v = xb[idx];
        float4 r;
        r.x = fmaxf(v.x - m.x, 0.f);
        r.y = fmaxf(v.y - m.y, 0.f);
        r.z = fmaxf(v.z - m.z, 0.f);
        r.w = fmaxf(v.w - m.w, 0.f);
        ob[idx] = r;
    }
}

extern "C" void kernel_launch(void* const* d_in, const int* in_sizes, int n_in,
                              void* d_out, int out_size, void* d_ws, size_t ws_size,
                              hipStream_t stream) {
    const float* x  = (const float*)d_in[0];   // [B, C, H, W] fp32
    // d_in[1] is k (int) — irrelevant to the forward value.
    float* out = (float*)d_out;

    const int groups = B_DIM * HW4;            // 12544
    dim3 grid(groups / TX);                    // 784 blocks
    dim3 block(256);
    hipLaunchKernelGGL(kwinners_fwd, grid, block, 0, stream, x, out);
}

// Round 2
// 43.385 us; speedup vs baseline: 1.4057x; 1.4057x over previous
//
#include <hip/hip_runtime.h>

// Problem: x [B=64, C=512, H=28, W=28] fp32.
// Forward math reduces to: out = relu(x - mean_over_C(x)) per (b,h,w).
// (top_k mask and stop_gradient only affect the backward pass.)
//
// Round-2 structure: register-resident single-read.
//   block = 256 threads = TX(8) float4-position-groups x TY(32) channel slices
//   each thread: load 16 float4 (its 16 channels x 4 positions) -> keep in VGPRs
//   reduce: __shfl_xor over the 8 ty-slices inside each wave (3 steps),
//           then ONE barrier + 4-partial LDS combine across the 4 waves
//   store: relu(v - mean) straight from registers (no second global read)

#define B_DIM 64
#define C_DIM 512
#define HW4   196               // 28*28/4 float4 groups per (b,c)
#define TX    8                 // float4-groups per block
#define TY    32                // channel slices
#define CPT   (C_DIM / TY)      // 16 channels per thread

__global__ __launch_bounds__(256, 4) void kwinners_fwd(const float* __restrict__ x,
                                                       float* __restrict__ out) {
    __shared__ float4 part[4][TX];      // one partial per (wave, tx): 512 B

    const int tid = threadIdx.x;
    const int tx  = tid & (TX - 1);     // 0..7
    const int ty  = tid >> 3;           // 0..31
    const int w   = tid >> 6;           // wave id 0..3

    const int g   = blockIdx.x * TX + tx;   // global float4-group index
    const int b   = g / HW4;
    const int hw4 = g - b * HW4;

    const float4* __restrict__ xb =
        reinterpret_cast<const float4*>(x) + (size_t)b * C_DIM * HW4 + hw4;
    float4* __restrict__ ob =
        reinterpret_cast<float4*>(out) + (size_t)b * C_DIM * HW4 + hw4;

    const int c0 = ty * CPT;

    // ---- single global read: 16 float4 into registers ----
    float4 v[CPT];
    #pragma unroll
    for (int cc = 0; cc < CPT; ++cc) {
        v[cc] = xb[(c0 + cc) * HW4];
    }

    // ---- per-thread partial sum ----
    float4 s = make_float4(0.f, 0.f, 0.f, 0.f);
    #pragma unroll
    for (int cc = 0; cc < CPT; ++cc) {
        s.x += v[cc].x; s.y += v[cc].y; s.z += v[cc].z; s.w += v[cc].w;
    }

    // ---- wave-level reduce across the 8 ty-slices in this wave ----
    // lanes differing in bits 3..5 share tx; xor-reduce them.
    #pragma unroll
    for (int m = 8; m <= 32; m <<= 1) {
        s.x += __shfl_xor(s.x, m);
        s.y += __shfl_xor(s.y, m);
        s.z += __shfl_xor(s.z, m);
        s.w += __shfl_xor(s.w, m);
    }

    // ---- combine the 4 per-wave partials (one barrier) ----
    if ((tid & 63) < TX) part[w][tx] = s;
    __syncthreads();

    float4 t0 = part[0][tx], t1 = part[1][tx], t2 = part[2][tx], t3 = part[3][tx];
    const float inv = 1.0f / (float)C_DIM;
    float4 m4;
    m4.x = (t0.x + t1.x + t2.x + t3.x) * inv;
    m4.y = (t0.y + t1.y + t2.y + t3.y) * inv;
    m4.z = (t0.z + t1.z + t2.z + t3.z) * inv;
    m4.w = (t0.w + t1.w + t2.w + t3.w) * inv;

    // ---- store relu(v - mean) from registers: no second global read ----
    #pragma unroll
    for (int cc = 0; cc < CPT; ++cc) {
        float4 r;
        r.x = fmaxf(v[cc].x - m4.x, 0.f);
        r.y = fmaxf(v[cc].y - m4.y, 0.f);
        r.z = fmaxf(v[cc].z - m4.z, 0.f);
        r.w = fmaxf(v[cc].w - m4.w, 0.f);
        ob[(c0 + cc) * HW4] = r;
    }
}

extern "C" void kernel_launch(void* const* d_in, const int* in_sizes, int n_in,
                              void* d_out, int out_size, void* d_ws, size_t ws_size,
                              hipStream_t stream) {
    const float* x  = (const float*)d_in[0];   // [B, C, H, W] fp32
    float* out = (float*)d_out;

    const int groups = B_DIM * HW4;            // 12544 float4 groups
    dim3 grid(groups / TX);                    // 1568 blocks
    dim3 block(256);
    hipLaunchKernelGGL(kwinners_fwd, grid, block, 0, stream, x, out);
}

// Round 3
// 43.358 us; speedup vs baseline: 1.4065x; 1.0006x over previous
//
#include <hip/hip_runtime.h>

// Problem: x [B=64, C=512, H=28, W=28] fp32.
// Forward math reduces to: out = relu(x - mean_over_C(x)) per (b,h,w).
// (top_k mask and stop_gradient only affect the backward pass.)
//
// Round-3 structure: maximize wave count (latency-bound fix).
//   block = 512 threads (8 waves) = TX(8) float4-groups x TY(64) channel slices
//   CPT = 8 channels/thread -> total waves = 12544 (49/CU demanded, chip
//   capacity 32/CU -> fully saturated), VGPR ~ 50 -> 8 waves/SIMD cap.
//   reduce: 3-step __shfl_xor within wave, ONE barrier, 8 wave-partials in LDS.
//   store: relu(v - mean) straight from registers (single global read).

#define B_DIM 64
#define C_DIM 512
#define HW4   196               // 28*28/4 float4 groups per (b,c)
#define TX    8                 // float4-groups per block
#define TY    64                // channel slices
#define CPT   (C_DIM / TY)      // 8 channels per thread
#define NW    8                 // waves per block (512 threads)

__global__ __launch_bounds__(512, 8) void kwinners_fwd(const float* __restrict__ x,
                                                       float* __restrict__ out) {
    __shared__ float4 part[NW][TX];     // 1 KB

    const int tid = threadIdx.x;
    const int tx  = tid & (TX - 1);     // 0..7
    const int ty  = tid >> 3;           // 0..63
    const int w   = tid >> 6;           // wave id 0..7

    const int g   = blockIdx.x * TX + tx;   // global float4-group index
    const int b   = g / HW4;
    const int hw4 = g - b * HW4;

    const float4* __restrict__ xb =
        reinterpret_cast<const float4*>(x) + (size_t)b * C_DIM * HW4 + hw4;
    float4* __restrict__ ob =
        reinterpret_cast<float4*>(out) + (size_t)b * C_DIM * HW4 + hw4;

    const int c0 = ty * CPT;

    // ---- single global read: 8 float4 into registers ----
    float4 v[CPT];
    #pragma unroll
    for (int cc = 0; cc < CPT; ++cc) {
        v[cc] = xb[(c0 + cc) * HW4];
    }

    // ---- per-thread partial sum ----
    float4 s = make_float4(0.f, 0.f, 0.f, 0.f);
    #pragma unroll
    for (int cc = 0; cc < CPT; ++cc) {
        s.x += v[cc].x; s.y += v[cc].y; s.z += v[cc].z; s.w += v[cc].w;
    }

    // ---- wave-level reduce across the 8 ty-slices in this wave ----
    // lanes sharing tx differ in tid bits 3..5
    #pragma unroll
    for (int m = 8; m <= 32; m <<= 1) {
        s.x += __shfl_xor(s.x, m);
        s.y += __shfl_xor(s.y, m);
        s.z += __shfl_xor(s.z, m);
        s.w += __shfl_xor(s.w, m);
    }

    // ---- combine the 8 per-wave partials (one barrier) ----
    if ((tid & 63) < TX) part[w][tx] = s;
    __syncthreads();

    float4 m4 = make_float4(0.f, 0.f, 0.f, 0.f);
    #pragma unroll
    for (int ww = 0; ww < NW; ++ww) {
        float4 p = part[ww][tx];
        m4.x += p.x; m4.y += p.y; m4.z += p.z; m4.w += p.w;
    }
    const float inv = 1.0f / (float)C_DIM;
    m4.x *= inv; m4.y *= inv; m4.z *= inv; m4.w *= inv;

    // ---- store relu(v - mean) from registers: no second global read ----
    #pragma unroll
    for (int cc = 0; cc < CPT; ++cc) {
        float4 r;
        r.x = fmaxf(v[cc].x - m4.x, 0.f);
        r.y = fmaxf(v[cc].y - m4.y, 0.f);
        r.z = fmaxf(v[cc].z - m4.z, 0.f);
        r.w = fmaxf(v[cc].w - m4.w, 0.f);
        ob[(c0 + cc) * HW4] = r;
    }
}

extern "C" void kernel_launch(void* const* d_in, const int* in_sizes, int n_in,
                              void* d_out, int out_size, void* d_ws, size_t ws_size,
                              hipStream_t stream) {
    const float* x  = (const float*)d_in[0];   // [B, C, H, W] fp32
    float* out = (float*)d_out;

    const int groups = B_DIM * HW4;            // 12544 float4 groups
    dim3 grid(groups / TX);                    // 1568 blocks x 8 waves = 12544 waves
    dim3 block(512);
    hipLaunchKernelGGL(kwinners_fwd, grid, block, 0, stream, x, out);
}

// Round 5
// 40.083 us; speedup vs baseline: 1.5214x; 1.0817x over previous
//
#include <hip/hip_runtime.h>

// Problem: x [B=64, C=512, H=28, W=28] fp32.
// Forward math reduces to: out = relu(x - mean_over_C(x)) per (b,h,w).
// (top_k mask and stop_gradient only affect the backward pass.)
//
// Round-4 (resubmit; previous attempt hit an unresponsive container):
// memory-pattern fixes (kernel is VMEM-throughput-bound at ~4.1 TB/s).
//  - TX=16: each wave-load covers 4x 256B contiguous segments (was 8x 128B).
//  - non-temporal float4 stores: out is never re-read by the kernel; nt keeps
//    out from evicting x in the 256MB Infinity Cache, so replay reads of x
//    are L3-served.
//  - still single global read, register-resident, 1 barrier.

#define B_DIM 64
#define C_DIM 512
#define HW4   196               // 28*28/4 float4 groups per (b,c)
#define TX    16                // float4-groups per block (256B per ty-slice segment)
#define TY    32                // channel slices
#define CPT   (C_DIM / TY)      // 16 channels per thread
#define NW    8                 // waves per block (512 threads)

typedef __attribute__((ext_vector_type(4))) float f4;

__global__ __launch_bounds__(512) void kwinners_fwd(const float* __restrict__ x,
                                                    float* __restrict__ out) {
    __shared__ f4 part[NW][TX];     // 2 KB

    const int tid = threadIdx.x;
    const int tx  = tid & (TX - 1);     // 0..15
    const int ty  = tid >> 4;           // 0..31
    const int w   = tid >> 6;           // wave id 0..7

    const int g   = blockIdx.x * TX + tx;   // global float4-group index
    const int b   = g / HW4;
    const int hw4 = g - b * HW4;

    const f4* __restrict__ xb =
        reinterpret_cast<const f4*>(x) + (size_t)b * C_DIM * HW4 + hw4;
    f4* __restrict__ ob =
        reinterpret_cast<f4*>(out) + (size_t)b * C_DIM * HW4 + hw4;

    const int c0 = ty * CPT;

    // ---- single global read: 16 float4 into registers ----
    f4 v[CPT];
    #pragma unroll
    for (int cc = 0; cc < CPT; ++cc) {
        v[cc] = xb[(c0 + cc) * HW4];
    }

    // ---- per-thread partial sum ----
    f4 s = (f4)(0.0f);
    #pragma unroll
    for (int cc = 0; cc < CPT; ++cc) s += v[cc];

    // ---- wave-level reduce: lanes sharing tx differ in tid bits 4,5 ----
    #pragma unroll
    for (int m = 16; m <= 32; m <<= 1) {
        s.x += __shfl_xor(s.x, m);
        s.y += __shfl_xor(s.y, m);
        s.z += __shfl_xor(s.z, m);
        s.w += __shfl_xor(s.w, m);
    }

    // ---- combine the 8 per-wave partials (one barrier) ----
    if ((tid & 63) < TX) part[w][tx] = s;
    __syncthreads();

    f4 m4 = (f4)(0.0f);
    #pragma unroll
    for (int ww = 0; ww < NW; ++ww) m4 += part[ww][tx];
    m4 *= (1.0f / (float)C_DIM);

    // ---- store relu(v - mean) from registers, non-temporal ----
    #pragma unroll
    for (int cc = 0; cc < CPT; ++cc) {
        f4 r = v[cc] - m4;
        r.x = fmaxf(r.x, 0.f);
        r.y = fmaxf(r.y, 0.f);
        r.z = fmaxf(r.z, 0.f);
        r.w = fmaxf(r.w, 0.f);
        __builtin_nontemporal_store(r, &ob[(c0 + cc) * HW4]);
    }
}

extern "C" void kernel_launch(void* const* d_in, const int* in_sizes, int n_in,
                              void* d_out, int out_size, void* d_ws, size_t ws_size,
                              hipStream_t stream) {
    const float* x  = (const float*)d_in[0];   // [B, C, H, W] fp32
    float* out = (float*)d_out;

    const int groups = B_DIM * HW4;            // 12544 float4 groups
    dim3 grid(groups / TX);                    // 784 blocks x 8 waves
    dim3 block(512);
    hipLaunchKernelGGL(kwinners_fwd, grid, block, 0, stream, x, out);
}